// Round 1
// baseline (201.894 us; speedup 1.0000x reference)
//
#include <hip/hip_runtime.h>

typedef __attribute__((ext_vector_type(8))) short bf16x8;
typedef __attribute__((ext_vector_type(4))) float f32x4;
typedef __attribute__((ext_vector_type(8))) unsigned short u16x8;
typedef __attribute__((ext_vector_type(4))) unsigned short u16x4;

#define DM 2048
#define DI 4096
#define DSTATE 16
#define DTR 128
#define BATCH 128

__device__ __forceinline__ unsigned short f2bf(float f) {
  union { float f; unsigned u; } v; v.f = f;
  unsigned r = v.u + 0x7FFFu + ((v.u >> 16) & 1u);
  return (unsigned short)(r >> 16);
}
__device__ __forceinline__ float sigm(float x) { return 1.f / (1.f + __expf(-x)); }

constexpr int BK = 64;
constexpr int LDT = BK + 8;  // +8 bf16 = 16B pad: keeps ds_read_b128 conflicts at free 2-way

template<int ROWS>
__device__ __forceinline__ void stage_bf16(const unsigned short* g, int ld, long r0, int c0,
                                           unsigned short* s, int tid) {
#pragma unroll
  for (int i = 0; i < ROWS * 8 / 256; ++i) {
    int idx = tid + i * 256;
    int r = idx >> 3, c = (idx & 7) * 8;
    *(u16x8*)&s[r * LDT + c] = *(const u16x8*)&g[(r0 + r) * (long)ld + c0 + c];
  }
}

template<int ROWS>
__device__ __forceinline__ void stage_f32(const float* g, int ld, long r0, int c0,
                                          unsigned short* s, int tid) {
#pragma unroll
  for (int i = 0; i < ROWS * 16 / 256; ++i) {
    int idx = tid + i * 256;
    int r = idx >> 4, c = (idx & 15) * 4;
    f32x4 v = *(const f32x4*)&g[(r0 + r) * (long)ld + c0 + c];
    u16x4 o;
    o[0] = f2bf(v[0]); o[1] = f2bf(v[1]); o[2] = f2bf(v[2]); o[3] = f2bf(v[3]);
    *(u16x4*)&s[r * LDT + c] = o;
  }
}

// Block = 256 threads = 4 waves in 2x2. Wave tile = 32 x (BN/2).
// acc layout: acc[mi*NF + ni]; D elem (row = wm*32+mi*16+(lane>>4)*4+r, col = wn*16*NF+ni*16+(lane&15))
template<int BM, int BN, bool ABF>
__device__ __forceinline__ void gemm_core(const void* Ag, int lda, const float* Bg, int ldb,
                                          int m0, int n0, int k0, int k1,
                                          unsigned short* As, unsigned short* Bs, f32x4* acc) {
  constexpr int NF = BN / 32;
  int tid = threadIdx.x;
  int lane = tid & 63, wave = tid >> 6;
  int wm = wave >> 1, wn = wave & 1;
  int llo = lane & 15, lhi = lane >> 4;
  for (int kb = k0; kb < k1; kb += BK) {
    if constexpr (ABF) stage_bf16<BM>((const unsigned short*)Ag, lda, m0, kb, As, tid);
    else               stage_f32<BM>((const float*)Ag, lda, m0, kb, As, tid);
    stage_f32<BN>(Bg, ldb, n0, kb, Bs, tid);
    __syncthreads();
#pragma unroll
    for (int kk = 0; kk < BK; kk += 32) {
      int kr = kk + lhi * 8;
      bf16x8 af[2], bf[NF];
#pragma unroll
      for (int mi = 0; mi < 2; ++mi)
        af[mi] = *(const bf16x8*)&As[(wm * 32 + mi * 16 + llo) * LDT + kr];
#pragma unroll
      for (int ni = 0; ni < NF; ++ni)
        bf[ni] = *(const bf16x8*)&Bs[(wn * 16 * NF + ni * 16 + llo) * LDT + kr];
#pragma unroll
      for (int mi = 0; mi < 2; ++mi)
#pragma unroll
        for (int ni = 0; ni < NF; ++ni)
          acc[mi * NF + ni] =
              __builtin_amdgcn_mfma_f32_16x16x32_bf16(af[mi], bf[ni], acc[mi * NF + ni], 0, 0, 0);
    }
    __syncthreads();
  }
}

// ---------------- K1: RMSNorm -> normed (bf16) ----------------
__global__ __launch_bounds__(256) void k1_rmsnorm(const float* __restrict__ hs,
                                                  const float* __restrict__ nw,
                                                  unsigned short* __restrict__ normed) {
  int b = blockIdx.x, tid = threadIdx.x;
  const float* xr = hs + (long)b * DM;
  f32x4 v0 = *(const f32x4*)&xr[tid * 4];
  f32x4 v1 = *(const f32x4*)&xr[(tid + 256) * 4];
  float ss = v0[0]*v0[0] + v0[1]*v0[1] + v0[2]*v0[2] + v0[3]*v0[3]
           + v1[0]*v1[0] + v1[1]*v1[1] + v1[2]*v1[2] + v1[3]*v1[3];
  for (int off = 32; off; off >>= 1) ss += __shfl_xor(ss, off);
  __shared__ float red[4];
  if ((tid & 63) == 0) red[tid >> 6] = ss;
  __syncthreads();
  ss = red[0] + red[1] + red[2] + red[3];
  float rstd = rsqrtf(ss * (1.f / DM) + 1e-5f);
  f32x4 w0 = *(const f32x4*)&nw[tid * 4];
  f32x4 w1 = *(const f32x4*)&nw[(tid + 256) * 4];
  u16x4 o0, o1;
#pragma unroll
  for (int j = 0; j < 4; ++j) {
    o0[j] = f2bf(v0[j] * rstd * w0[j]);
    o1[j] = f2bf(v1[j] * rstd * w1[j]);
  }
  *(u16x4*)&normed[(long)b * DM + tid * 4] = o0;
  *(u16x4*)&normed[(long)b * DM + (tid + 256) * 4] = o1;
}

// ---------------- K2: in_proj GEMM (128x8192x2048) + conv/silu epilogue ----------------
__global__ __launch_bounds__(256) void k2_inproj(
    const unsigned short* __restrict__ normed, const float* __restrict__ W,
    const float* __restrict__ conv_state, const float* __restrict__ conv_w,
    const float* __restrict__ conv_b, float* __restrict__ out_ncs, float* __restrict__ xact_f,
    unsigned short* __restrict__ xact_b, float* __restrict__ szf, float* __restrict__ proj) {
  int tid = threadIdx.x;
  int gid = (blockIdx.y * gridDim.x + blockIdx.x) * 256 + tid;
  if (gid < BATCH * 160) proj[gid] = 0.f;  // zero proj for K3's atomics
  __shared__ unsigned short As[64 * LDT], Bs[64 * LDT];
  f32x4 acc[4] = {};
  int bn = blockIdx.x, bm = blockIdx.y;
  gemm_core<64, 64, true>(normed, DM, W, DM, bm * 64, bn * 64, 0, DM, As, Bs, acc);
  int lane = tid & 63, wave = tid >> 6, wm = wave >> 1, wn = wave & 1;
  int llo = lane & 15, lhi = lane >> 4;
#pragma unroll
  for (int ni = 0; ni < 2; ++ni) {
    int n = bn * 64 + wn * 32 + ni * 16 + llo;  // 0..8191; tile is entirely one side of 4096
    if (n < DI) {
      float w0 = conv_w[n * 4], w1 = conv_w[n * 4 + 1], w2 = conv_w[n * 4 + 2], w3 = conv_w[n * 4 + 3];
      float cb = conv_b[n];
#pragma unroll
      for (int mi = 0; mi < 2; ++mi)
#pragma unroll
        for (int r = 0; r < 4; ++r) {
          int b = bm * 64 + wm * 32 + mi * 16 + lhi * 4 + r;
          float xc = acc[mi * 2 + ni][r];
          const float* cs = conv_state + ((long)b * DI + n) * 3;
          float c1 = cs[1], c2 = cs[2];
          float xs = cs[0] * w0 + c1 * w1 + c2 * w2 + xc * w3 + cb;
          float xa = xs * sigm(xs);
          float* ncs = out_ncs + ((long)b * DI + n) * 3;
          ncs[0] = c1; ncs[1] = c2; ncs[2] = xc;
          xact_f[(long)b * DI + n] = xa;
          xact_b[(long)b * DI + n] = f2bf(xa);
        }
    } else {
      int n2 = n - DI;
#pragma unroll
      for (int mi = 0; mi < 2; ++mi)
#pragma unroll
        for (int r = 0; r < 4; ++r) {
          int b = bm * 64 + wm * 32 + mi * 16 + lhi * 4 + r;
          float z = acc[mi * 2 + ni][r];
          szf[(long)b * DI + n2] = z * sigm(z);
        }
    }
  }
}

// ---------------- K3: x_proj GEMM (128x160x4096), split-K=8, atomic accumulate ----------------
__global__ __launch_bounds__(256) void k3_xproj(const unsigned short* __restrict__ xact_b,
                                                const float* __restrict__ XW,
                                                float* __restrict__ proj) {
  __shared__ unsigned short As[64 * LDT], Bs[32 * LDT];
  f32x4 acc[2] = {};
  int bn = blockIdx.x, bm = blockIdx.y, kc = blockIdx.z;
  gemm_core<64, 32, true>(xact_b, DI, XW, DI, bm * 64, bn * 32, kc * 512, kc * 512 + 512, As, Bs, acc);
  int tid = threadIdx.x, lane = tid & 63, wave = tid >> 6, wm = wave >> 1, wn = wave & 1;
  int llo = lane & 15, lhi = lane >> 4;
  int n = bn * 32 + wn * 16 + llo;  // < 160
#pragma unroll
  for (int mi = 0; mi < 2; ++mi)
#pragma unroll
    for (int r = 0; r < 4; ++r) {
      int b = bm * 64 + wm * 32 + mi * 16 + lhi * 4 + r;
      atomicAdd(&proj[b * 160 + n], acc[mi][r]);
    }
}

// ---------------- K4: dt GEMM (128x4096x128) + softplus + SSM update + y*silu(z) ----------------
__global__ __launch_bounds__(256) void k4_dtssm(
    const float* __restrict__ proj, const float* __restrict__ DW, const float* __restrict__ dtb,
    const float* __restrict__ A_log, const float* __restrict__ Dp, const float* __restrict__ ssm,
    const float* __restrict__ xact_f, const float* __restrict__ szf, float* __restrict__ out_nss,
    unsigned short* __restrict__ yz_b) {
  __shared__ unsigned short As[64 * LDT], Bs[32 * LDT];
  f32x4 acc[2] = {};
  int bn = blockIdx.x, bm = blockIdx.y;
  gemm_core<64, 32, false>(proj, 160, DW, DTR, bm * 64, bn * 32, 0, DTR, As, Bs, acc);
  int tid = threadIdx.x, lane = tid & 63, wave = tid >> 6, wm = wave >> 1, wn = wave & 1;
  int llo = lane & 15, lhi = lane >> 4;
  int n = bn * 32 + wn * 16 + llo;
  float dtbn = dtb[n], Dn = Dp[n];
  float aS[16];
#pragma unroll
  for (int s = 0; s < 16; ++s) aS[s] = -__expf(A_log[n * 16 + s]);
#pragma unroll
  for (int mi = 0; mi < 2; ++mi)
#pragma unroll
    for (int r = 0; r < 4; ++r) {
      int b = bm * 64 + wm * 32 + mi * 16 + lhi * 4 + r;
      float dtv = acc[mi][r] + dtbn;
      dtv = (dtv > 20.f) ? dtv : log1pf(__expf(dtv));
      float xa = xact_f[(long)b * DI + n];
      float szv = szf[(long)b * DI + n];
      const float* Bp = proj + b * 160 + 128;
      const float* Cp = proj + b * 160 + 144;
      const float* sp = ssm + ((long)b * DI + n) * 16;
      float* np = out_nss + ((long)b * DI + n) * 16;
      float y = 0.f;
#pragma unroll
      for (int q = 0; q < 4; ++q) {
        f32x4 sv = *(const f32x4*)&sp[q * 4];
        f32x4 Bv = *(const f32x4*)&Bp[q * 4];
        f32x4 Cv = *(const f32x4*)&Cp[q * 4];
        f32x4 nv;
#pragma unroll
        for (int j = 0; j < 4; ++j) {
          float dA = __expf(dtv * aS[q * 4 + j]);
          nv[j] = sv[j] * dA + dtv * Bv[j] * xa;
          y += nv[j] * Cv[j];
        }
        *(f32x4*)&np[q * 4] = nv;
      }
      y = (y + Dn * xa) * szv;
      yz_b[(long)b * DI + n] = f2bf(y);
    }
}

// ---------------- K5: out_proj GEMM (128x2048x4096) + residual ----------------
__global__ __launch_bounds__(256) void k5_outproj(const unsigned short* __restrict__ yz_b,
                                                  const float* __restrict__ OW,
                                                  const float* __restrict__ hs,
                                                  float* __restrict__ outp) {
  __shared__ unsigned short As[64 * LDT], Bs[32 * LDT];
  f32x4 acc[2] = {};
  int bn = blockIdx.x, bm = blockIdx.y;
  gemm_core<64, 32, true>(yz_b, DI, OW, DI, bm * 64, bn * 32, 0, DI, As, Bs, acc);
  int tid = threadIdx.x, lane = tid & 63, wave = tid >> 6, wm = wave >> 1, wn = wave & 1;
  int llo = lane & 15, lhi = lane >> 4;
  int n = bn * 32 + wn * 16 + llo;
#pragma unroll
  for (int mi = 0; mi < 2; ++mi)
#pragma unroll
    for (int r = 0; r < 4; ++r) {
      int b = bm * 64 + wm * 32 + mi * 16 + lhi * 4 + r;
      outp[(long)b * DM + n] = acc[mi][r] + hs[(long)b * DM + n];
    }
}

extern "C" void kernel_launch(void* const* d_in, const int* in_sizes, int n_in, void* d_out,
                              int out_size, void* d_ws, size_t ws_size, hipStream_t stream) {
  const float* hs         = (const float*)d_in[0];
  const float* conv_state = (const float*)d_in[1];
  const float* ssm        = (const float*)d_in[2];
  const float* norm_w     = (const float*)d_in[3];
  const float* in_proj_w  = (const float*)d_in[4];
  const float* conv_w     = (const float*)d_in[5];
  const float* conv_b     = (const float*)d_in[6];
  const float* x_proj_w   = (const float*)d_in[7];
  const float* dt_proj_w  = (const float*)d_in[8];
  const float* dt_proj_b  = (const float*)d_in[9];
  const float* A_log      = (const float*)d_in[10];
  const float* Dp         = (const float*)d_in[11];
  const float* out_proj_w = (const float*)d_in[12];

  float* outp    = (float*)d_out;                 // (128,1,2048)
  float* out_ncs = outp + 262144;                 // (128,4096,3)
  float* out_nss = outp + 262144 + 1572864;       // (128,4096,16)

  char* ws = (char*)d_ws;
  unsigned short* normed = (unsigned short*)(ws);            // 128x2048 bf16
  float*          xact_f = (float*)(ws + 524288);            // 128x4096 f32
  unsigned short* xact_b = (unsigned short*)(ws + 2621440);  // 128x4096 bf16
  float*          szf    = (float*)(ws + 3670016);           // 128x4096 f32 silu(z)
  float*          proj   = (float*)(ws + 5767168);           // 128x160 f32
  unsigned short* yz_b   = (unsigned short*)(ws + 5849088);  // 128x4096 bf16

  hipLaunchKernelGGL(k1_rmsnorm, dim3(128), dim3(256), 0, stream, hs, norm_w, normed);
  hipLaunchKernelGGL(k2_inproj, dim3(128, 2), dim3(256), 0, stream, normed, in_proj_w, conv_state,
                     conv_w, conv_b, out_ncs, xact_f, xact_b, szf, proj);
  hipLaunchKernelGGL(k3_xproj, dim3(5, 2, 8), dim3(256), 0, stream, xact_b, x_proj_w, proj);
  hipLaunchKernelGGL(k4_dtssm, dim3(128, 2), dim3(256), 0, stream, proj, dt_proj_w, dt_proj_b,
                     A_log, Dp, ssm, xact_f, szf, out_nss, yz_b);
  hipLaunchKernelGGL(k5_outproj, dim3(64, 2), dim3(256), 0, stream, yz_b, out_proj_w, hs, outp);
}

// Round 2
// 89.610 us; speedup vs baseline: 2.2530x; 2.2530x over previous
//
#include <hip/hip_runtime.h>

typedef __attribute__((ext_vector_type(8))) short bf16x8;
typedef __attribute__((ext_vector_type(4))) float f32x4;
typedef __attribute__((ext_vector_type(8))) unsigned short u16x8;
typedef __attribute__((ext_vector_type(4))) unsigned short u16x4;

#define DM 2048
#define DI 4096
#define BATCH 128

__device__ __forceinline__ unsigned short f2bf(float f) {
  union { float f; unsigned u; } v; v.f = f;
  unsigned r = v.u + 0x7FFFu + ((v.u >> 16) & 1u);
  return (unsigned short)(r >> 16);
}
__device__ __forceinline__ float bf2f(unsigned short u) {
  union { unsigned u; float f; } v; v.u = (unsigned)u << 16; return v.f;
}
__device__ __forceinline__ float sigm(float x) { return 1.f / (1.f + __expf(-x)); }

constexpr int BK = 64;
constexpr int LDT = BK + 8;  // +16B pad: ds_read_b128/write conflicts stay at free 2-way

// M is always 128 (the batch). 256 threads = 4 waves as 2M x 2N.
// Wave tile: 64 x (BN/2). acc[mi*NF+ni]; D elem row = wm*64+mi*16+(lane>>4)*4+r,
// col = wn*16*NF + ni*16 + (lane&15).
// Double-buffered: reg-stage next K-tile's global loads BEFORE compute, LDS-write after,
// ONE barrier per K-step (writes go to the opposite buffer).
template<int BN, bool ABF>
__device__ __forceinline__ void gemm128(const void* Ag, int lda, const float* Bg, int ldb,
                                        int n0, int k0, int k1, unsigned short* lds,
                                        f32x4* acc) {
  constexpr int NF = BN / 32;
  constexpr int BUF = (128 + BN) * LDT;
  const int tid = threadIdx.x, lane = tid & 63, wave = tid >> 6;
  const int wm = wave >> 1, wn = wave & 1, llo = lane & 15, lhi = lane >> 4;

  u16x8 ar[ABF ? 4 : 1];
  f32x4 arf[ABF ? 1 : 8];
  f32x4 br[BN / 16];

  auto ldregs = [&](int kb) {
    if constexpr (ABF) {
#pragma unroll
      for (int i = 0; i < 4; ++i) {
        int idx = tid + i * 256, r = idx >> 3, c = (idx & 7) * 8;
        ar[i] = *(const u16x8*)&((const unsigned short*)Ag)[(long)r * lda + kb + c];
      }
    } else {
#pragma unroll
      for (int i = 0; i < 8; ++i) {
        int idx = tid + i * 256, r = idx >> 4, c = (idx & 15) * 4;
        arf[i] = *(const f32x4*)&((const float*)Ag)[(long)r * lda + kb + c];
      }
    }
#pragma unroll
    for (int i = 0; i < BN / 16; ++i) {
      int idx = tid + i * 256, r = idx >> 4, c = (idx & 15) * 4;
      br[i] = *(const f32x4*)&Bg[(long)(n0 + r) * ldb + kb + c];
    }
  };

  auto stlds = [&](int buf) {
    unsigned short* As = lds + buf * BUF;
    unsigned short* Bs = As + 128 * LDT;
    if constexpr (ABF) {
#pragma unroll
      for (int i = 0; i < 4; ++i) {
        int idx = tid + i * 256, r = idx >> 3, c = (idx & 7) * 8;
        *(u16x8*)&As[r * LDT + c] = ar[i];
      }
    } else {
#pragma unroll
      for (int i = 0; i < 8; ++i) {
        int idx = tid + i * 256, r = idx >> 4, c = (idx & 15) * 4;
        u16x4 o; o[0] = f2bf(arf[i][0]); o[1] = f2bf(arf[i][1]);
        o[2] = f2bf(arf[i][2]); o[3] = f2bf(arf[i][3]);
        *(u16x4*)&As[r * LDT + c] = o;
      }
    }
#pragma unroll
    for (int i = 0; i < BN / 16; ++i) {
      int idx = tid + i * 256, r = idx >> 4, c = (idx & 15) * 4;
      u16x4 o; o[0] = f2bf(br[i][0]); o[1] = f2bf(br[i][1]);
      o[2] = f2bf(br[i][2]); o[3] = f2bf(br[i][3]);
      *(u16x4*)&Bs[r * LDT + c] = o;
    }
  };

  ldregs(k0);
  stlds(0);
  __syncthreads();
  const int nt = (k1 - k0) / BK;
  int cur = 0;
  for (int t = 0; t < nt; ++t) {
    if (t + 1 < nt) ldregs(k0 + (t + 1) * BK);
    const unsigned short* As = lds + cur * BUF;
    const unsigned short* Bs = As + 128 * LDT;
#pragma unroll
    for (int kk = 0; kk < BK; kk += 32) {
      int kr = kk + lhi * 8;
      bf16x8 af[4], bf[NF];
#pragma unroll
      for (int mi = 0; mi < 4; ++mi)
        af[mi] = *(const bf16x8*)&As[(wm * 64 + mi * 16 + llo) * LDT + kr];
#pragma unroll
      for (int ni = 0; ni < NF; ++ni)
        bf[ni] = *(const bf16x8*)&Bs[(wn * 16 * NF + ni * 16 + llo) * LDT + kr];
#pragma unroll
      for (int mi = 0; mi < 4; ++mi)
#pragma unroll
        for (int ni = 0; ni < NF; ++ni)
          acc[mi * NF + ni] =
              __builtin_amdgcn_mfma_f32_16x16x32_bf16(af[mi], bf[ni], acc[mi * NF + ni], 0, 0, 0);
    }
    if (t + 1 < nt) stlds(cur ^ 1);
    __syncthreads();
    cur ^= 1;
  }
}

// ---------------- K1: RMSNorm -> normed (bf16) ----------------
__global__ __launch_bounds__(256) void k1_rmsnorm(const float* __restrict__ hs,
                                                  const float* __restrict__ nw,
                                                  unsigned short* __restrict__ normed) {
  int b = blockIdx.x, tid = threadIdx.x;
  const float* xr = hs + (long)b * DM;
  f32x4 v0 = *(const f32x4*)&xr[tid * 4];
  f32x4 v1 = *(const f32x4*)&xr[(tid + 256) * 4];
  float ss = v0[0]*v0[0] + v0[1]*v0[1] + v0[2]*v0[2] + v0[3]*v0[3]
           + v1[0]*v1[0] + v1[1]*v1[1] + v1[2]*v1[2] + v1[3]*v1[3];
  for (int off = 32; off; off >>= 1) ss += __shfl_xor(ss, off);
  __shared__ float red[4];
  if ((tid & 63) == 0) red[tid >> 6] = ss;
  __syncthreads();
  ss = red[0] + red[1] + red[2] + red[3];
  float rstd = rsqrtf(ss * (1.f / DM) + 1e-5f);
  f32x4 w0 = *(const f32x4*)&nw[tid * 4];
  f32x4 w1 = *(const f32x4*)&nw[(tid + 256) * 4];
  u16x4 o0, o1;
#pragma unroll
  for (int j = 0; j < 4; ++j) {
    o0[j] = f2bf(v0[j] * rstd * w0[j]);
    o1[j] = f2bf(v1[j] * rstd * w1[j]);
  }
  *(u16x4*)&normed[(long)b * DM + tid * 4] = o0;
  *(u16x4*)&normed[(long)b * DM + (tid + 256) * 4] = o1;
}

// ---------------- K2: in_proj GEMM (128x8192x2048), split-K=4, atomic into xz ----------------
__global__ __launch_bounds__(256) void k2_inproj(const unsigned short* __restrict__ normed,
                                                 const float* __restrict__ W,
                                                 float* __restrict__ xz) {
  __shared__ unsigned short lds[2 * (128 + 64) * LDT];
  f32x4 acc[8] = {};
  int bn = blockIdx.x, sk = blockIdx.y;
  gemm128<64, true>(normed, DM, W, DM, bn * 64, sk * 512, sk * 512 + 512, lds, acc);
  int tid = threadIdx.x, lane = tid & 63, wave = tid >> 6, wm = wave >> 1, wn = wave & 1;
  int llo = lane & 15, lhi = lane >> 4;
#pragma unroll
  for (int mi = 0; mi < 4; ++mi)
#pragma unroll
    for (int ni = 0; ni < 2; ++ni)
#pragma unroll
      for (int r = 0; r < 4; ++r) {
        int b = wm * 64 + mi * 16 + lhi * 4 + r;
        int n = bn * 64 + wn * 32 + ni * 16 + llo;
        atomicAdd(&xz[(long)b * 8192 + n], acc[mi * 2 + ni][r]);
      }
}

// ---------------- E2: conv + SiLU epilogue ----------------
__global__ __launch_bounds__(256) void e2_conv(const float* __restrict__ xz,
                                               const float* __restrict__ conv_state,
                                               const float* __restrict__ conv_w,
                                               const float* __restrict__ conv_b,
                                               float* __restrict__ out_ncs,
                                               float* __restrict__ xact_f,
                                               unsigned short* __restrict__ xact_b,
                                               unsigned short* __restrict__ szb) {
  int p = blockIdx.x * 256 + threadIdx.x;  // (b,n) pair, n fastest
  int b = p >> 12, n = p & 4095;
  float xc = xz[(long)b * 8192 + n];
  float z  = xz[(long)b * 8192 + DI + n];
  const float* cs = conv_state + (long)p * 3;
  float c0 = cs[0], c1 = cs[1], c2 = cs[2];
  f32x4 cw = *(const f32x4*)&conv_w[n * 4];
  float xs = c0 * cw[0] + c1 * cw[1] + c2 * cw[2] + xc * cw[3] + conv_b[n];
  float xa = xs * sigm(xs);
  float* ncs = out_ncs + (long)p * 3;
  ncs[0] = c1; ncs[1] = c2; ncs[2] = xc;
  xact_f[p] = xa;
  xact_b[p] = f2bf(xa);
  szb[p] = f2bf(z * sigm(z));
}

// ---------------- K3: x_proj GEMM (128x160x4096), split-K=16, atomic into proj ----------------
__global__ __launch_bounds__(256) void k3_xproj(const unsigned short* __restrict__ xact_b,
                                                const float* __restrict__ XW,
                                                float* __restrict__ proj) {
  __shared__ unsigned short lds[2 * (128 + 32) * LDT];
  f32x4 acc[4] = {};
  int bn = blockIdx.x, kc = blockIdx.y;
  gemm128<32, true>(xact_b, DI, XW, DI, bn * 32, kc * 256, kc * 256 + 256, lds, acc);
  int tid = threadIdx.x, lane = tid & 63, wave = tid >> 6, wm = wave >> 1, wn = wave & 1;
  int llo = lane & 15, lhi = lane >> 4;
  int n = bn * 32 + wn * 16 + llo;
#pragma unroll
  for (int mi = 0; mi < 4; ++mi)
#pragma unroll
    for (int r = 0; r < 4; ++r) {
      int b = wm * 64 + mi * 16 + lhi * 4 + r;
      atomicAdd(&proj[b * 160 + n], acc[mi][r]);
    }
}

// ---------------- K4a: dt GEMM (128x4096x128) + softplus -> dt_f ----------------
__global__ __launch_bounds__(256) void k4a_dt(const float* __restrict__ proj,
                                              const float* __restrict__ DW,
                                              const float* __restrict__ dtb,
                                              float* __restrict__ dt_f) {
  __shared__ unsigned short lds[2 * (128 + 64) * LDT];
  f32x4 acc[8] = {};
  int bn = blockIdx.x;
  gemm128<64, false>(proj, 160, DW, 128, bn * 64, 0, 128, lds, acc);
  int tid = threadIdx.x, lane = tid & 63, wave = tid >> 6, wm = wave >> 1, wn = wave & 1;
  int llo = lane & 15, lhi = lane >> 4;
#pragma unroll
  for (int mi = 0; mi < 4; ++mi)
#pragma unroll
    for (int ni = 0; ni < 2; ++ni) {
      int n = bn * 64 + wn * 32 + ni * 16 + llo;
      float db = dtb[n];
#pragma unroll
      for (int r = 0; r < 4; ++r) {
        int b = wm * 64 + mi * 16 + lhi * 4 + r;
        float v = acc[mi * 2 + ni][r] + db;
        dt_f[(long)b * DI + n] = (v > 20.f) ? v : log1pf(__expf(v));
      }
    }
}

// ---------------- K4b: SSM state update + y*silu(z) -> yz_b, nss ----------------
// 4 lanes per (b,n): each lane handles 4 states; quad shfl-reduce for y.
__global__ __launch_bounds__(256) void k4b_ssm(const float* __restrict__ dt_f,
                                               const float* __restrict__ proj,
                                               const float* __restrict__ A_log,
                                               const float* __restrict__ Dp,
                                               const float* __restrict__ ssm,
                                               const float* __restrict__ xact_f,
                                               const unsigned short* __restrict__ szb,
                                               float* __restrict__ out_nss,
                                               unsigned short* __restrict__ yz_b) {
  int t = blockIdx.x * 256 + threadIdx.x;
  int s4 = t & 3;
  int p0 = t >> 2;
  const int STRIDE = (2048 * 256) >> 2;  // 131072 quads
#pragma unroll
  for (int it = 0; it < 4; ++it) {
    int p = p0 + it * STRIDE;  // (b,n) pair
    int b = p >> 12, n = p & 4095;
    float dtv = dt_f[p];
    float xa = xact_f[p];
    f32x4 sv = *(const f32x4*)&ssm[(long)p * 16 + s4 * 4];
    f32x4 Al = *(const f32x4*)&A_log[n * 16 + s4 * 4];
    f32x4 Bv = *(const f32x4*)&proj[b * 160 + 128 + s4 * 4];
    f32x4 Cv = *(const f32x4*)&proj[b * 160 + 144 + s4 * 4];
    f32x4 nv;
    float y = 0.f;
#pragma unroll
    for (int j = 0; j < 4; ++j) {
      float dA = __expf(dtv * (-__expf(Al[j])));
      nv[j] = sv[j] * dA + dtv * Bv[j] * xa;
      y += nv[j] * Cv[j];
    }
    *(f32x4*)&out_nss[(long)p * 16 + s4 * 4] = nv;
    y += __shfl_xor(y, 1);
    y += __shfl_xor(y, 2);
    if (s4 == 0) yz_b[p] = f2bf((y + Dp[n] * xa) * bf2f(szb[p]));
  }
}

// ---------------- K5: out_proj GEMM (128x2048x4096), split-K=8, atomic into outp ----------------
__global__ __launch_bounds__(256) void k5_outproj(const unsigned short* __restrict__ yz_b,
                                                  const float* __restrict__ OW,
                                                  float* __restrict__ outp) {
  __shared__ unsigned short lds[2 * (128 + 32) * LDT];
  f32x4 acc[4] = {};
  int bn = blockIdx.x, sk = blockIdx.y;
  gemm128<32, true>(yz_b, DI, OW, DI, bn * 32, sk * 512, sk * 512 + 512, lds, acc);
  int tid = threadIdx.x, lane = tid & 63, wave = tid >> 6, wm = wave >> 1, wn = wave & 1;
  int llo = lane & 15, lhi = lane >> 4;
  int n = bn * 32 + wn * 16 + llo;
#pragma unroll
  for (int mi = 0; mi < 4; ++mi)
#pragma unroll
    for (int r = 0; r < 4; ++r) {
      int b = wm * 64 + mi * 16 + lhi * 4 + r;
      atomicAdd(&outp[(long)b * DM + n], acc[mi][r]);
    }
}

extern "C" void kernel_launch(void* const* d_in, const int* in_sizes, int n_in, void* d_out,
                              int out_size, void* d_ws, size_t ws_size, hipStream_t stream) {
  const float* hs         = (const float*)d_in[0];
  const float* conv_state = (const float*)d_in[1];
  const float* ssm        = (const float*)d_in[2];
  const float* norm_w     = (const float*)d_in[3];
  const float* in_proj_w  = (const float*)d_in[4];
  const float* conv_w     = (const float*)d_in[5];
  const float* conv_b     = (const float*)d_in[6];
  const float* x_proj_w   = (const float*)d_in[7];
  const float* dt_proj_w  = (const float*)d_in[8];
  const float* dt_proj_b  = (const float*)d_in[9];
  const float* A_log      = (const float*)d_in[10];
  const float* Dp         = (const float*)d_in[11];
  const float* out_proj_w = (const float*)d_in[12];

  float* outp    = (float*)d_out;               // (128,1,2048)
  float* out_ncs = outp + 262144;               // (128,4096,3)
  float* out_nss = outp + 262144 + 1572864;     // (128,4096,16)

  char* ws = (char*)d_ws;
  unsigned short* normed = (unsigned short*)(ws);             // 128x2048 bf16 (dead after K2)
  float*          dt_f   = (float*)(ws);                      // 128x4096 f32 (aliases normed)
  float*          xz     = (float*)(ws + 2097152);            // 128x8192 f32
  unsigned short* yz_b   = (unsigned short*)(ws + 2097152);   // 128x4096 bf16 (aliases xz, dead)
  float*          xact_f = (float*)(ws + 6291456);            // 128x4096 f32
  unsigned short* xact_b = (unsigned short*)(ws + 8388608);   // 128x4096 bf16
  unsigned short* szb    = (unsigned short*)(ws + 9437184);   // 128x4096 bf16 silu(z)
  float*          proj   = (float*)(ws + 10485760);           // 128x160 f32

  hipMemsetAsync(xz, 0, 4194304, stream);
  hipMemsetAsync(proj, 0, 81920, stream);
  hipMemcpyAsync(outp, hs, 262144 * 4, hipMemcpyDeviceToDevice, stream);

  hipLaunchKernelGGL(k1_rmsnorm, dim3(128), dim3(256), 0, stream, hs, norm_w, normed);
  hipLaunchKernelGGL(k2_inproj, dim3(128, 4), dim3(256), 0, stream, normed, in_proj_w, xz);
  hipLaunchKernelGGL(e2_conv, dim3(2048), dim3(256), 0, stream, xz, conv_state, conv_w, conv_b,
                     out_ncs, xact_f, xact_b, szb);
  hipLaunchKernelGGL(k3_xproj, dim3(5, 16), dim3(256), 0, stream, xact_b, x_proj_w, proj);
  hipLaunchKernelGGL(k4a_dt, dim3(64), dim3(256), 0, stream, proj, dt_proj_w, dt_proj_b, dt_f);
  hipLaunchKernelGGL(k4b_ssm, dim3(2048), dim3(256), 0, stream, dt_f, proj, A_log, Dp, ssm,
                     xact_f, szb, out_nss, yz_b);
  hipLaunchKernelGGL(k5_outproj, dim3(64, 8), dim3(256), 0, stream, yz_b, out_proj_w, outp);
}

// Round 3
// 85.157 us; speedup vs baseline: 2.3708x; 1.0523x over previous
//
#include <hip/hip_runtime.h>

typedef __attribute__((ext_vector_type(8))) short bf16x8;
typedef __attribute__((ext_vector_type(4))) float f32x4;
typedef __attribute__((ext_vector_type(8))) unsigned short u16x8;
typedef __attribute__((ext_vector_type(4))) unsigned short u16x4;

#define DM 2048
#define DI 4096
#define BATCH 128

__device__ __forceinline__ unsigned short f2bf(float f) {
  union { float f; unsigned u; } v; v.f = f;
  unsigned r = v.u + 0x7FFFu + ((v.u >> 16) & 1u);
  return (unsigned short)(r >> 16);
}
__device__ __forceinline__ float bf2f(unsigned short u) {
  union { unsigned u; float f; } v; v.u = (unsigned)u << 16; return v.f;
}
__device__ __forceinline__ float sigm(float x) { return 1.f / (1.f + __expf(-x)); }

constexpr int BK = 64;
constexpr int LDT = BK + 8;  // +16B pad: ds_read_b128/write conflicts stay at free 2-way

// M is always 128 (the batch). 256 threads = 4 waves as 2M x 2N.
// Wave tile: 64 x (BN/2). acc[mi*NF+ni]; D elem row = wm*64+mi*16+(lane>>4)*4+r,
// col = wn*16*NF + ni*16 + (lane&15).
// Double-buffered: reg-stage next K-tile's global loads BEFORE compute, LDS-write after,
// ONE barrier per K-step (writes go to the opposite buffer).
template<int BN, bool ABF>
__device__ __forceinline__ void gemm128(const void* Ag, int lda, const float* Bg, int ldb,
                                        int n0, int k0, int k1, unsigned short* lds,
                                        f32x4* acc) {
  constexpr int NF = BN / 32;
  constexpr int BUF = (128 + BN) * LDT;
  const int tid = threadIdx.x, lane = tid & 63, wave = tid >> 6;
  const int wm = wave >> 1, wn = wave & 1, llo = lane & 15, lhi = lane >> 4;

  u16x8 ar[ABF ? 4 : 1];
  f32x4 arf[ABF ? 1 : 8];
  f32x4 br[BN / 16];

  auto ldregs = [&](int kb) {
    if constexpr (ABF) {
#pragma unroll
      for (int i = 0; i < 4; ++i) {
        int idx = tid + i * 256, r = idx >> 3, c = (idx & 7) * 8;
        ar[i] = *(const u16x8*)&((const unsigned short*)Ag)[(long)r * lda + kb + c];
      }
    } else {
#pragma unroll
      for (int i = 0; i < 8; ++i) {
        int idx = tid + i * 256, r = idx >> 4, c = (idx & 15) * 4;
        arf[i] = *(const f32x4*)&((const float*)Ag)[(long)r * lda + kb + c];
      }
    }
#pragma unroll
    for (int i = 0; i < BN / 16; ++i) {
      int idx = tid + i * 256, r = idx >> 4, c = (idx & 15) * 4;
      br[i] = *(const f32x4*)&Bg[(long)(n0 + r) * ldb + kb + c];
    }
  };

  auto stlds = [&](int buf) {
    unsigned short* As = lds + buf * BUF;
    unsigned short* Bs = As + 128 * LDT;
    if constexpr (ABF) {
#pragma unroll
      for (int i = 0; i < 4; ++i) {
        int idx = tid + i * 256, r = idx >> 3, c = (idx & 7) * 8;
        *(u16x8*)&As[r * LDT + c] = ar[i];
      }
    } else {
#pragma unroll
      for (int i = 0; i < 8; ++i) {
        int idx = tid + i * 256, r = idx >> 4, c = (idx & 15) * 4;
        u16x4 o; o[0] = f2bf(arf[i][0]); o[1] = f2bf(arf[i][1]);
        o[2] = f2bf(arf[i][2]); o[3] = f2bf(arf[i][3]);
        *(u16x4*)&As[r * LDT + c] = o;
      }
    }
#pragma unroll
    for (int i = 0; i < BN / 16; ++i) {
      int idx = tid + i * 256, r = idx >> 4, c = (idx & 15) * 4;
      u16x4 o; o[0] = f2bf(br[i][0]); o[1] = f2bf(br[i][1]);
      o[2] = f2bf(br[i][2]); o[3] = f2bf(br[i][3]);
      *(u16x4*)&Bs[r * LDT + c] = o;
    }
  };

  ldregs(k0);
  stlds(0);
  __syncthreads();
  const int nt = (k1 - k0) / BK;
  int cur = 0;
  for (int t = 0; t < nt; ++t) {
    if (t + 1 < nt) ldregs(k0 + (t + 1) * BK);
    const unsigned short* As = lds + cur * BUF;
    const unsigned short* Bs = As + 128 * LDT;
#pragma unroll
    for (int kk = 0; kk < BK; kk += 32) {
      int kr = kk + lhi * 8;
      bf16x8 af[4], bf[NF];
#pragma unroll
      for (int mi = 0; mi < 4; ++mi)
        af[mi] = *(const bf16x8*)&As[(wm * 64 + mi * 16 + llo) * LDT + kr];
#pragma unroll
      for (int ni = 0; ni < NF; ++ni)
        bf[ni] = *(const bf16x8*)&Bs[(wn * 16 * NF + ni * 16 + llo) * LDT + kr];
#pragma unroll
      for (int mi = 0; mi < 4; ++mi)
#pragma unroll
        for (int ni = 0; ni < NF; ++ni)
          acc[mi * NF + ni] =
              __builtin_amdgcn_mfma_f32_16x16x32_bf16(af[mi], bf[ni], acc[mi * NF + ni], 0, 0, 0);
    }
    if (t + 1 < nt) stlds(cur ^ 1);
    __syncthreads();
    cur ^= 1;
  }
}

// ---------------- K0: prep — zero xz & proj, copy hs -> outp ----------------
__global__ __launch_bounds__(256) void k0_prep(const float* __restrict__ hs,
                                               float* __restrict__ outp,
                                               float* __restrict__ xz,
                                               float* __restrict__ proj) {
  int t = blockIdx.x * 256 + threadIdx.x;  // 0..262143
  f32x4 z = {};
  *(f32x4*)&xz[t * 4] = z;
  if (t < 65536) *(f32x4*)&outp[t * 4] = *(const f32x4*)&hs[t * 4];
  if (t < 5120) *(f32x4*)&proj[t * 4] = z;
}

// ---------------- K1: RMSNorm -> normed (bf16) ----------------
__global__ __launch_bounds__(256) void k1_rmsnorm(const float* __restrict__ hs,
                                                  const float* __restrict__ nw,
                                                  unsigned short* __restrict__ normed) {
  int b = blockIdx.x, tid = threadIdx.x;
  const float* xr = hs + (long)b * DM;
  f32x4 v0 = *(const f32x4*)&xr[tid * 4];
  f32x4 v1 = *(const f32x4*)&xr[(tid + 256) * 4];
  float ss = v0[0]*v0[0] + v0[1]*v0[1] + v0[2]*v0[2] + v0[3]*v0[3]
           + v1[0]*v1[0] + v1[1]*v1[1] + v1[2]*v1[2] + v1[3]*v1[3];
  for (int off = 32; off; off >>= 1) ss += __shfl_xor(ss, off);
  __shared__ float red[4];
  if ((tid & 63) == 0) red[tid >> 6] = ss;
  __syncthreads();
  ss = red[0] + red[1] + red[2] + red[3];
  float rstd = rsqrtf(ss * (1.f / DM) + 1e-5f);
  f32x4 w0 = *(const f32x4*)&nw[tid * 4];
  f32x4 w1 = *(const f32x4*)&nw[(tid + 256) * 4];
  u16x4 o0, o1;
#pragma unroll
  for (int j = 0; j < 4; ++j) {
    o0[j] = f2bf(v0[j] * rstd * w0[j]);
    o1[j] = f2bf(v1[j] * rstd * w1[j]);
  }
  *(u16x4*)&normed[(long)b * DM + tid * 4] = o0;
  *(u16x4*)&normed[(long)b * DM + (tid + 256) * 4] = o1;
}

// ---------------- K2: in_proj GEMM (128x8192x2048), split-K=4, atomic into xz ----------------
__global__ __launch_bounds__(256) void k2_inproj(const unsigned short* __restrict__ normed,
                                                 const float* __restrict__ W,
                                                 float* __restrict__ xz) {
  __shared__ unsigned short lds[2 * (128 + 64) * LDT];
  f32x4 acc[8] = {};
  int bn = blockIdx.x, sk = blockIdx.y;
  gemm128<64, true>(normed, DM, W, DM, bn * 64, sk * 512, sk * 512 + 512, lds, acc);
  int tid = threadIdx.x, lane = tid & 63, wave = tid >> 6, wm = wave >> 1, wn = wave & 1;
  int llo = lane & 15, lhi = lane >> 4;
#pragma unroll
  for (int mi = 0; mi < 4; ++mi)
#pragma unroll
    for (int ni = 0; ni < 2; ++ni)
#pragma unroll
      for (int r = 0; r < 4; ++r) {
        int b = wm * 64 + mi * 16 + lhi * 4 + r;
        int n = bn * 64 + wn * 32 + ni * 16 + llo;
        atomicAdd(&xz[(long)b * 8192 + n], acc[mi * 2 + ni][r]);
      }
}

// ---------------- E2: conv + SiLU epilogue ----------------
__global__ __launch_bounds__(256) void e2_conv(const float* __restrict__ xz,
                                               const float* __restrict__ conv_state,
                                               const float* __restrict__ conv_w,
                                               const float* __restrict__ conv_b,
                                               float* __restrict__ out_ncs,
                                               float* __restrict__ xact_f,
                                               unsigned short* __restrict__ xact_b,
                                               unsigned short* __restrict__ szb) {
  int p = blockIdx.x * 256 + threadIdx.x;  // (b,n) pair, n fastest
  int b = p >> 12, n = p & 4095;
  float xc = xz[(long)b * 8192 + n];
  float z  = xz[(long)b * 8192 + DI + n];
  const float* cs = conv_state + (long)p * 3;
  float c0 = cs[0], c1 = cs[1], c2 = cs[2];
  f32x4 cw = *(const f32x4*)&conv_w[n * 4];
  float xs = c0 * cw[0] + c1 * cw[1] + c2 * cw[2] + xc * cw[3] + conv_b[n];
  float xa = xs * sigm(xs);
  float* ncs = out_ncs + (long)p * 3;
  ncs[0] = c1; ncs[1] = c2; ncs[2] = xc;
  xact_f[p] = xa;
  xact_b[p] = f2bf(xa);
  szb[p] = f2bf(z * sigm(z));
}

// ---------------- K3: x_proj GEMM (128x160x4096), split-K=16, atomic into proj ----------------
__global__ __launch_bounds__(256) void k3_xproj(const unsigned short* __restrict__ xact_b,
                                                const float* __restrict__ XW,
                                                float* __restrict__ proj) {
  __shared__ unsigned short lds[2 * (128 + 32) * LDT];
  f32x4 acc[4] = {};
  int bn = blockIdx.x, kc = blockIdx.y;
  gemm128<32, true>(xact_b, DI, XW, DI, bn * 32, kc * 256, kc * 256 + 256, lds, acc);
  int tid = threadIdx.x, lane = tid & 63, wave = tid >> 6, wm = wave >> 1, wn = wave & 1;
  int llo = lane & 15, lhi = lane >> 4;
  int n = bn * 32 + wn * 16 + llo;
#pragma unroll
  for (int mi = 0; mi < 4; ++mi)
#pragma unroll
    for (int r = 0; r < 4; ++r) {
      int b = wm * 64 + mi * 16 + lhi * 4 + r;
      atomicAdd(&proj[b * 160 + n], acc[mi][r]);
    }
}

// ---------------- K4a: dt GEMM (128x4096x128) + softplus -> dt_f ----------------
__global__ __launch_bounds__(256) void k4a_dt(const float* __restrict__ proj,
                                              const float* __restrict__ DW,
                                              const float* __restrict__ dtb,
                                              float* __restrict__ dt_f) {
  __shared__ unsigned short lds[2 * (128 + 64) * LDT];
  f32x4 acc[8] = {};
  int bn = blockIdx.x;
  gemm128<64, false>(proj, 160, DW, 128, bn * 64, 0, 128, lds, acc);
  int tid = threadIdx.x, lane = tid & 63, wave = tid >> 6, wm = wave >> 1, wn = wave & 1;
  int llo = lane & 15, lhi = lane >> 4;
#pragma unroll
  for (int mi = 0; mi < 4; ++mi)
#pragma unroll
    for (int ni = 0; ni < 2; ++ni) {
      int n = bn * 64 + wn * 32 + ni * 16 + llo;
      float db = dtb[n];
#pragma unroll
      for (int r = 0; r < 4; ++r) {
        int b = wm * 64 + mi * 16 + lhi * 4 + r;
        float v = acc[mi * 2 + ni][r] + db;
        dt_f[(long)b * DI + n] = (v > 20.f) ? v : log1pf(__expf(v));
      }
    }
}

// ---------------- K4b: SSM state update + y*silu(z) -> yz_b, nss ----------------
// 4 lanes per (b,n): each lane handles 4 states; quad shfl-reduce for y.
__global__ __launch_bounds__(256) void k4b_ssm(const float* __restrict__ dt_f,
                                               const float* __restrict__ proj,
                                               const float* __restrict__ A_log,
                                               const float* __restrict__ Dp,
                                               const float* __restrict__ ssm,
                                               const float* __restrict__ xact_f,
                                               const unsigned short* __restrict__ szb,
                                               float* __restrict__ out_nss,
                                               unsigned short* __restrict__ yz_b) {
  int t = blockIdx.x * 256 + threadIdx.x;
  int s4 = t & 3;
  int p0 = t >> 2;
  const int STRIDE = (2048 * 256) >> 2;  // 131072 quads
#pragma unroll
  for (int it = 0; it < 4; ++it) {
    int p = p0 + it * STRIDE;  // (b,n) pair
    int b = p >> 12, n = p & 4095;
    float dtv = dt_f[p];
    float xa = xact_f[p];
    f32x4 sv = *(const f32x4*)&ssm[(long)p * 16 + s4 * 4];
    f32x4 Al = *(const f32x4*)&A_log[n * 16 + s4 * 4];
    f32x4 Bv = *(const f32x4*)&proj[b * 160 + 128 + s4 * 4];
    f32x4 Cv = *(const f32x4*)&proj[b * 160 + 144 + s4 * 4];
    f32x4 nv;
    float y = 0.f;
#pragma unroll
    for (int j = 0; j < 4; ++j) {
      float dA = __expf(dtv * (-__expf(Al[j])));
      nv[j] = sv[j] * dA + dtv * Bv[j] * xa;
      y += nv[j] * Cv[j];
    }
    *(f32x4*)&out_nss[(long)p * 16 + s4 * 4] = nv;
    y += __shfl_xor(y, 1);
    y += __shfl_xor(y, 2);
    if (s4 == 0) yz_b[p] = f2bf((y + Dp[n] * xa) * bf2f(szb[p]));
  }
}

// ---------------- K5: out_proj GEMM (128x2048x4096), split-K=8, atomic into outp ----------------
__global__ __launch_bounds__(256) void k5_outproj(const unsigned short* __restrict__ yz_b,
                                                  const float* __restrict__ OW,
                                                  float* __restrict__ outp) {
  __shared__ unsigned short lds[2 * (128 + 32) * LDT];
  f32x4 acc[4] = {};
  int bn = blockIdx.x, sk = blockIdx.y;
  gemm128<32, true>(yz_b, DI, OW, DI, bn * 32, sk * 512, sk * 512 + 512, lds, acc);
  int tid = threadIdx.x, lane = tid & 63, wave = tid >> 6, wm = wave >> 1, wn = wave & 1;
  int llo = lane & 15, lhi = lane >> 4;
  int n = bn * 32 + wn * 16 + llo;
#pragma unroll
  for (int mi = 0; mi < 4; ++mi)
#pragma unroll
    for (int r = 0; r < 4; ++r) {
      int b = wm * 64 + mi * 16 + lhi * 4 + r;
      atomicAdd(&outp[(long)b * DM + n], acc[mi][r]);
    }
}

extern "C" void kernel_launch(void* const* d_in, const int* in_sizes, int n_in, void* d_out,
                              int out_size, void* d_ws, size_t ws_size, hipStream_t stream) {
  const float* hs         = (const float*)d_in[0];
  const float* conv_state = (const float*)d_in[1];
  const float* ssm        = (const float*)d_in[2];
  const float* norm_w     = (const float*)d_in[3];
  const float* in_proj_w  = (const float*)d_in[4];
  const float* conv_w     = (const float*)d_in[5];
  const float* conv_b     = (const float*)d_in[6];
  const float* x_proj_w   = (const float*)d_in[7];
  const float* dt_proj_w  = (const float*)d_in[8];
  const float* dt_proj_b  = (const float*)d_in[9];
  const float* A_log      = (const float*)d_in[10];
  const float* Dp         = (const float*)d_in[11];
  const float* out_proj_w = (const float*)d_in[12];

  float* outp    = (float*)d_out;               // (128,1,2048)
  float* out_ncs = outp + 262144;               // (128,4096,3)
  float* out_nss = outp + 262144 + 1572864;     // (128,4096,16)

  char* ws = (char*)d_ws;
  unsigned short* normed = (unsigned short*)(ws);             // 128x2048 bf16 (dead after K2)
  float*          dt_f   = (float*)(ws);                      // 128x4096 f32 (aliases normed)
  float*          xz     = (float*)(ws + 2097152);            // 128x8192 f32
  unsigned short* yz_b   = (unsigned short*)(ws + 2097152);   // 128x4096 bf16 (aliases xz, dead)
  float*          xact_f = (float*)(ws + 6291456);            // 128x4096 f32
  unsigned short* xact_b = (unsigned short*)(ws + 8388608);   // 128x4096 bf16
  unsigned short* szb    = (unsigned short*)(ws + 9437184);   // 128x4096 bf16 silu(z)
  float*          proj   = (float*)(ws + 10485760);           // 128x160 f32

  hipLaunchKernelGGL(k0_prep, dim3(1024), dim3(256), 0, stream, hs, outp, xz, proj);
  hipLaunchKernelGGL(k1_rmsnorm, dim3(128), dim3(256), 0, stream, hs, norm_w, normed);
  hipLaunchKernelGGL(k2_inproj, dim3(128, 4), dim3(256), 0, stream, normed, in_proj_w, xz);
  hipLaunchKernelGGL(e2_conv, dim3(2048), dim3(256), 0, stream, xz, conv_state, conv_w, conv_b,
                     out_ncs, xact_f, xact_b, szb);
  hipLaunchKernelGGL(k3_xproj, dim3(5, 16), dim3(256), 0, stream, xact_b, x_proj_w, proj);
  hipLaunchKernelGGL(k4a_dt, dim3(64), dim3(256), 0, stream, proj, dt_proj_w, dt_proj_b, dt_f);
  hipLaunchKernelGGL(k4b_ssm, dim3(2048), dim3(256), 0, stream, dt_f, proj, A_log, Dp, ssm,
                     xact_f, szb, out_nss, yz_b);
  hipLaunchKernelGGL(k5_outproj, dim3(64, 8), dim3(256), 0, stream, yz_b, out_proj_w, outp);
}

// Round 4
// 76.756 us; speedup vs baseline: 2.6303x; 1.1094x over previous
//
#include <hip/hip_runtime.h>

typedef __attribute__((ext_vector_type(8))) short bf16x8;
typedef __attribute__((ext_vector_type(4))) float f32x4;
typedef __attribute__((ext_vector_type(8))) unsigned short u16x8;
typedef __attribute__((ext_vector_type(4))) unsigned short u16x4;

#define DM 2048
#define DI 4096
#define BATCH 128

__device__ __forceinline__ unsigned short f2bf(float f) {
  union { float f; unsigned u; } v; v.f = f;
  unsigned r = v.u + 0x7FFFu + ((v.u >> 16) & 1u);
  return (unsigned short)(r >> 16);
}
__device__ __forceinline__ float bf2f(unsigned short u) {
  union { unsigned u; float f; } v; v.u = (unsigned)u << 16; return v.f;
}
__device__ __forceinline__ float sigm(float x) { return 1.f / (1.f + __expf(-x)); }

constexpr int BK = 64;
constexpr int LDT = BK + 8;  // +16B pad: ds_read_b128 conflicts stay <=4-way (cheap)

// ---- depth-2 software-pipelined GEMM, M=128, 256 threads = 4 waves (2M x 2N) ----
// Register sets are NAMED (ar0/ar1,...) so all indexing is compile-time (no scratch).
// Pipeline: tiles t use reg-set t%2 and LDS buf t%2. ldregs(t+2) issued before compute(t),
// stlds(t+1) after compute(t) -> the vmcnt wait for set (t+1) has set (t+2)'s 12 loads
// outstanding => counted wait, HBM latency hidden across ~2 K-steps.
#define LDREGS(AR, ARF, BR, kb_) do {                                                     \
    int kb = (kb_);                                                                       \
    if constexpr (ABF) {                                                                  \
      _Pragma("unroll") for (int i = 0; i < 4; ++i) {                                     \
        int idx = tid + i * 256, r = idx >> 3, c = (idx & 7) * 8;                         \
        AR[i] = *(const u16x8*)&((const unsigned short*)Ag)[(long)r * lda + kb + c];      \
      }                                                                                   \
    } else {                                                                              \
      _Pragma("unroll") for (int i = 0; i < 8; ++i) {                                     \
        int idx = tid + i * 256, r = idx >> 4, c = (idx & 15) * 4;                        \
        ARF[i] = *(const f32x4*)&((const float*)Ag)[(long)r * lda + kb + c];              \
      }                                                                                   \
    }                                                                                     \
    _Pragma("unroll") for (int i = 0; i < BN / 16; ++i) {                                 \
      int idx = tid + i * 256, r = idx >> 4, c = (idx & 15) * 4;                          \
      BR[i] = *(const f32x4*)&Bg[(long)(n0 + r) * ldb + kb + c];                          \
    }                                                                                     \
  } while (0)

#define STLDS(AR, ARF, BR, buf_) do {                                                     \
    unsigned short* As_ = lds + (buf_) * BUF;                                             \
    unsigned short* Bs_ = As_ + 128 * LDT;                                                \
    if constexpr (ABF) {                                                                  \
      _Pragma("unroll") for (int i = 0; i < 4; ++i) {                                     \
        int idx = tid + i * 256, r = idx >> 3, c = (idx & 7) * 8;                         \
        *(u16x8*)&As_[r * LDT + c] = AR[i];                                               \
      }                                                                                   \
    } else {                                                                              \
      _Pragma("unroll") for (int i = 0; i < 8; ++i) {                                     \
        int idx = tid + i * 256, r = idx >> 4, c = (idx & 15) * 4;                        \
        u16x4 o; o[0] = f2bf(ARF[i][0]); o[1] = f2bf(ARF[i][1]);                          \
        o[2] = f2bf(ARF[i][2]); o[3] = f2bf(ARF[i][3]);                                   \
        *(u16x4*)&As_[r * LDT + c] = o;                                                   \
      }                                                                                   \
    }                                                                                     \
    _Pragma("unroll") for (int i = 0; i < BN / 16; ++i) {                                 \
      int idx = tid + i * 256, r = idx >> 4, c = (idx & 15) * 4;                          \
      u16x4 o; o[0] = f2bf(BR[i][0]); o[1] = f2bf(BR[i][1]);                              \
      o[2] = f2bf(BR[i][2]); o[3] = f2bf(BR[i][3]);                                       \
      *(u16x4*)&Bs_[r * LDT + c] = o;                                                     \
    }                                                                                     \
  } while (0)

#define COMPUTE(buf_) do {                                                                \
    const unsigned short* As_ = lds + (buf_) * BUF;                                       \
    const unsigned short* Bs_ = As_ + 128 * LDT;                                          \
    _Pragma("unroll") for (int kk = 0; kk < BK; kk += 32) {                               \
      int kr = kk + lhi * 8;                                                              \
      bf16x8 af[4], bfr[NF];                                                              \
      _Pragma("unroll") for (int mi = 0; mi < 4; ++mi)                                    \
        af[mi] = *(const bf16x8*)&As_[(wm * 64 + mi * 16 + llo) * LDT + kr];              \
      _Pragma("unroll") for (int ni = 0; ni < NF; ++ni)                                   \
        bfr[ni] = *(const bf16x8*)&Bs_[(wn * 16 * NF + ni * 16 + llo) * LDT + kr];        \
      _Pragma("unroll") for (int mi = 0; mi < 4; ++mi)                                    \
        _Pragma("unroll") for (int ni = 0; ni < NF; ++ni)                                 \
          acc[mi * NF + ni] = __builtin_amdgcn_mfma_f32_16x16x32_bf16(                    \
              af[mi], bfr[ni], acc[mi * NF + ni], 0, 0, 0);                               \
    }                                                                                     \
  } while (0)

// requires nt = (k1-k0)/BK >= 2
template<int BN, bool ABF>
__device__ __forceinline__ void gemm128(const void* Ag, int lda, const float* Bg, int ldb,
                                        int n0, int k0, int k1, unsigned short* lds,
                                        f32x4* acc) {
  constexpr int NF = BN / 32;
  constexpr int BUF = (128 + BN) * LDT;
  const int tid = threadIdx.x, lane = tid & 63, wave = tid >> 6;
  const int wm = wave >> 1, wn = wave & 1, llo = lane & 15, lhi = lane >> 4;

  u16x8 ar0[ABF ? 4 : 1], ar1[ABF ? 4 : 1];
  f32x4 arf0[ABF ? 1 : 8], arf1[ABF ? 1 : 8];
  f32x4 br0[BN / 16], br1[BN / 16];

  const int nt = (k1 - k0) / BK;
  LDREGS(ar0, arf0, br0, k0);
  LDREGS(ar1, arf1, br1, k0 + BK);
  STLDS(ar0, arf0, br0, 0);
  __syncthreads();
  int t = 0;
  while (true) {
    // even tile: reg-set 0, buf 0
    if (t + 2 < nt) LDREGS(ar0, arf0, br0, k0 + (t + 2) * BK);
    COMPUTE(0);
    if (t + 1 < nt) STLDS(ar1, arf1, br1, 1);
    __syncthreads();
    if (++t == nt) break;
    // odd tile: reg-set 1, buf 1
    if (t + 2 < nt) LDREGS(ar1, arf1, br1, k0 + (t + 2) * BK);
    COMPUTE(1);
    if (t + 1 < nt) STLDS(ar0, arf0, br0, 0);
    __syncthreads();
    if (++t == nt) break;
  }
}

// ---------------- K01: RMSNorm + zero xz/proj + copy hs -> outp ----------------
__global__ __launch_bounds__(256) void k01_prep(const float* __restrict__ hs,
                                                const float* __restrict__ nw,
                                                unsigned short* __restrict__ normed,
                                                float* __restrict__ outp,
                                                float* __restrict__ xz,
                                                float* __restrict__ proj) {
  int blk = blockIdx.x, tid = threadIdx.x;
  int t = blk * 256 + tid;  // 0..262143
  f32x4 z = {};
  *(f32x4*)&xz[t * 4] = z;
  if (t < 65536) *(f32x4*)&outp[t * 4] = *(const f32x4*)&hs[t * 4];
  if (t < 5120) *(f32x4*)&proj[t * 4] = z;
  if (blk < 128) {
    int b = blk;
    const float* xr = hs + (long)b * DM;
    f32x4 v0 = *(const f32x4*)&xr[tid * 4];
    f32x4 v1 = *(const f32x4*)&xr[(tid + 256) * 4];
    float ss = v0[0]*v0[0] + v0[1]*v0[1] + v0[2]*v0[2] + v0[3]*v0[3]
             + v1[0]*v1[0] + v1[1]*v1[1] + v1[2]*v1[2] + v1[3]*v1[3];
    for (int off = 32; off; off >>= 1) ss += __shfl_xor(ss, off);
    __shared__ float red[4];
    if ((tid & 63) == 0) red[tid >> 6] = ss;
    __syncthreads();
    ss = red[0] + red[1] + red[2] + red[3];
    float rstd = rsqrtf(ss * (1.f / DM) + 1e-5f);
    f32x4 w0 = *(const f32x4*)&nw[tid * 4];
    f32x4 w1 = *(const f32x4*)&nw[(tid + 256) * 4];
    u16x4 o0, o1;
#pragma unroll
    for (int j = 0; j < 4; ++j) {
      o0[j] = f2bf(v0[j] * rstd * w0[j]);
      o1[j] = f2bf(v1[j] * rstd * w1[j]);
    }
    *(u16x4*)&normed[(long)b * DM + tid * 4] = o0;
    *(u16x4*)&normed[(long)b * DM + (tid + 256) * 4] = o1;
  }
}

// ---------------- K2: in_proj GEMM (128x8192x2048), split-K=4, atomic into xz ----------------
__global__ __launch_bounds__(256) void k2_inproj(const unsigned short* __restrict__ normed,
                                                 const float* __restrict__ W,
                                                 float* __restrict__ xz) {
  __shared__ unsigned short lds[2 * (128 + 64) * LDT];
  f32x4 acc[8] = {};
  int bn = blockIdx.x, sk = blockIdx.y;
  gemm128<64, true>(normed, DM, W, DM, bn * 64, sk * 512, sk * 512 + 512, lds, acc);
  int tid = threadIdx.x, lane = tid & 63, wave = tid >> 6, wm = wave >> 1, wn = wave & 1;
  int llo = lane & 15, lhi = lane >> 4;
#pragma unroll
  for (int mi = 0; mi < 4; ++mi)
#pragma unroll
    for (int ni = 0; ni < 2; ++ni)
#pragma unroll
      for (int r = 0; r < 4; ++r) {
        int b = wm * 64 + mi * 16 + lhi * 4 + r;
        int n = bn * 64 + wn * 32 + ni * 16 + llo;
        atomicAdd(&xz[(long)b * 8192 + n], acc[mi * 2 + ni][r]);
      }
}

// ---------------- E2: conv + SiLU epilogue ----------------
__global__ __launch_bounds__(256) void e2_conv(const float* __restrict__ xz,
                                               const float* __restrict__ conv_state,
                                               const float* __restrict__ conv_w,
                                               const float* __restrict__ conv_b,
                                               float* __restrict__ out_ncs,
                                               float* __restrict__ xact_f,
                                               unsigned short* __restrict__ xact_b,
                                               unsigned short* __restrict__ szb) {
  int p = blockIdx.x * 256 + threadIdx.x;  // (b,n) pair, n fastest
  int b = p >> 12, n = p & 4095;
  float xc = xz[(long)b * 8192 + n];
  float z  = xz[(long)b * 8192 + DI + n];
  const float* cs = conv_state + (long)p * 3;
  float c0 = cs[0], c1 = cs[1], c2 = cs[2];
  f32x4 cw = *(const f32x4*)&conv_w[n * 4];
  float xs = c0 * cw[0] + c1 * cw[1] + c2 * cw[2] + xc * cw[3] + conv_b[n];
  float xa = xs * sigm(xs);
  float* ncs = out_ncs + (long)p * 3;
  ncs[0] = c1; ncs[1] = c2; ncs[2] = xc;
  xact_f[p] = xa;
  xact_b[p] = f2bf(xa);
  szb[p] = f2bf(z * sigm(z));
}

// ---------------- K3: x_proj GEMM (128x160x4096), split-K=32, atomic into proj ----------------
__global__ __launch_bounds__(256) void k3_xproj(const unsigned short* __restrict__ xact_b,
                                                const float* __restrict__ XW,
                                                float* __restrict__ proj) {
  __shared__ unsigned short lds[2 * (128 + 32) * LDT];
  f32x4 acc[4] = {};
  int bn = blockIdx.x, kc = blockIdx.y;
  gemm128<32, true>(xact_b, DI, XW, DI, bn * 32, kc * 128, kc * 128 + 128, lds, acc);
  int tid = threadIdx.x, lane = tid & 63, wave = tid >> 6, wm = wave >> 1, wn = wave & 1;
  int llo = lane & 15, lhi = lane >> 4;
  int n = bn * 32 + wn * 16 + llo;
#pragma unroll
  for (int mi = 0; mi < 4; ++mi)
#pragma unroll
    for (int r = 0; r < 4; ++r) {
      int b = wm * 64 + mi * 16 + lhi * 4 + r;
      atomicAdd(&proj[b * 160 + n], acc[mi][r]);
    }
}

// ---------------- K4a: dt GEMM (128x4096x128) + softplus -> dt_f ----------------
__global__ __launch_bounds__(256) void k4a_dt(const float* __restrict__ proj,
                                              const float* __restrict__ DW,
                                              const float* __restrict__ dtb,
                                              float* __restrict__ dt_f) {
  __shared__ unsigned short lds[2 * (128 + 32) * LDT];
  f32x4 acc[4] = {};
  int bn = blockIdx.x;
  gemm128<32, false>(proj, 160, DW, 128, bn * 32, 0, 128, lds, acc);
  int tid = threadIdx.x, lane = tid & 63, wave = tid >> 6, wm = wave >> 1, wn = wave & 1;
  int llo = lane & 15, lhi = lane >> 4;
  int n = bn * 32 + wn * 16 + llo;
  float db = dtb[n];
#pragma unroll
  for (int mi = 0; mi < 4; ++mi)
#pragma unroll
    for (int r = 0; r < 4; ++r) {
      int b = wm * 64 + mi * 16 + lhi * 4 + r;
      float v = acc[mi][r] + db;
      dt_f[(long)b * DI + n] = (v > 20.f) ? v : log1pf(__expf(v));
    }
}

// ---------------- K4b: SSM state update + y*silu(z) -> yz_b, nss ----------------
__global__ __launch_bounds__(256) void k4b_ssm(const float* __restrict__ dt_f,
                                               const float* __restrict__ proj,
                                               const float* __restrict__ A_log,
                                               const float* __restrict__ Dp,
                                               const float* __restrict__ ssm,
                                               const float* __restrict__ xact_f,
                                               const unsigned short* __restrict__ szb,
                                               float* __restrict__ out_nss,
                                               unsigned short* __restrict__ yz_b) {
  int t = blockIdx.x * 256 + threadIdx.x;
  int s4 = t & 3;
  int p0 = t >> 2;
  const int STRIDE = (2048 * 256) >> 2;  // 131072 quads
#pragma unroll
  for (int it = 0; it < 4; ++it) {
    int p = p0 + it * STRIDE;  // (b,n) pair
    int b = p >> 12, n = p & 4095;
    float dtv = dt_f[p];
    float xa = xact_f[p];
    f32x4 sv = *(const f32x4*)&ssm[(long)p * 16 + s4 * 4];
    f32x4 Al = *(const f32x4*)&A_log[n * 16 + s4 * 4];
    f32x4 Bv = *(const f32x4*)&proj[b * 160 + 128 + s4 * 4];
    f32x4 Cv = *(const f32x4*)&proj[b * 160 + 144 + s4 * 4];
    f32x4 nv;
    float y = 0.f;
#pragma unroll
    for (int j = 0; j < 4; ++j) {
      float dA = __expf(dtv * (-__expf(Al[j])));
      nv[j] = sv[j] * dA + dtv * Bv[j] * xa;
      y += nv[j] * Cv[j];
    }
    *(f32x4*)&out_nss[(long)p * 16 + s4 * 4] = nv;
    y += __shfl_xor(y, 1);
    y += __shfl_xor(y, 2);
    if (s4 == 0) yz_b[p] = f2bf((y + Dp[n] * xa) * bf2f(szb[p]));
  }
}

// ---------------- K5: out_proj GEMM (128x2048x4096), split-K=8, atomic into outp ----------------
__global__ __launch_bounds__(256) void k5_outproj(const unsigned short* __restrict__ yz_b,
                                                  const float* __restrict__ OW,
                                                  float* __restrict__ outp) {
  __shared__ unsigned short lds[2 * (128 + 32) * LDT];
  f32x4 acc[4] = {};
  int bn = blockIdx.x, sk = blockIdx.y;
  gemm128<32, true>(yz_b, DI, OW, DI, bn * 32, sk * 512, sk * 512 + 512, lds, acc);
  int tid = threadIdx.x, lane = tid & 63, wave = tid >> 6, wm = wave >> 1, wn = wave & 1;
  int llo = lane & 15, lhi = lane >> 4;
  int n = bn * 32 + wn * 16 + llo;
#pragma unroll
  for (int mi = 0; mi < 4; ++mi)
#pragma unroll
    for (int r = 0; r < 4; ++r) {
      int b = wm * 64 + mi * 16 + lhi * 4 + r;
      atomicAdd(&outp[(long)b * DM + n], acc[mi][r]);
    }
}

extern "C" void kernel_launch(void* const* d_in, const int* in_sizes, int n_in, void* d_out,
                              int out_size, void* d_ws, size_t ws_size, hipStream_t stream) {
  const float* hs         = (const float*)d_in[0];
  const float* conv_state = (const float*)d_in[1];
  const float* ssm        = (const float*)d_in[2];
  const float* norm_w     = (const float*)d_in[3];
  const float* in_proj_w  = (const float*)d_in[4];
  const float* conv_w     = (const float*)d_in[5];
  const float* conv_b     = (const float*)d_in[6];
  const float* x_proj_w   = (const float*)d_in[7];
  const float* dt_proj_w  = (const float*)d_in[8];
  const float* dt_proj_b  = (const float*)d_in[9];
  const float* A_log      = (const float*)d_in[10];
  const float* Dp         = (const float*)d_in[11];
  const float* out_proj_w = (const float*)d_in[12];

  float* outp    = (float*)d_out;               // (128,1,2048)
  float* out_ncs = outp + 262144;               // (128,4096,3)
  float* out_nss = outp + 262144 + 1572864;     // (128,4096,16)

  char* ws = (char*)d_ws;
  unsigned short* normed = (unsigned short*)(ws);             // 128x2048 bf16 (dead after K2)
  float*          dt_f   = (float*)(ws);                      // 128x4096 f32 (aliases normed)
  float*          xz     = (float*)(ws + 2097152);            // 128x8192 f32
  unsigned short* yz_b   = (unsigned short*)(ws + 2097152);   // 128x4096 bf16 (aliases xz, dead)
  float*          xact_f = (float*)(ws + 6291456);            // 128x4096 f32
  unsigned short* xact_b = (unsigned short*)(ws + 8388608);   // 128x4096 bf16
  unsigned short* szb    = (unsigned short*)(ws + 9437184);   // 128x4096 bf16 silu(z)
  float*          proj   = (float*)(ws + 10485760);           // 128x160 f32

  hipLaunchKernelGGL(k01_prep, dim3(1024), dim3(256), 0, stream, hs, norm_w, normed, outp, xz, proj);
  hipLaunchKernelGGL(k2_inproj, dim3(128, 4), dim3(256), 0, stream, normed, in_proj_w, xz);
  hipLaunchKernelGGL(e2_conv, dim3(2048), dim3(256), 0, stream, xz, conv_state, conv_w, conv_b,
                     out_ncs, xact_f, xact_b, szb);
  hipLaunchKernelGGL(k3_xproj, dim3(5, 32), dim3(256), 0, stream, xact_b, x_proj_w, proj);
  hipLaunchKernelGGL(k4a_dt, dim3(128), dim3(256), 0, stream, proj, dt_proj_w, dt_proj_b, dt_f);
  hipLaunchKernelGGL(k4b_ssm, dim3(2048), dim3(256), 0, stream, dt_f, proj, A_log, Dp, ssm,
                     xact_f, szb, out_nss, yz_b);
  hipLaunchKernelGGL(k5_outproj, dim3(64, 8), dim3(256), 0, stream, yz_b, out_proj_w, outp);
}